// Round 1
// baseline (85.581 us; speedup 1.0000x reference)
//
#include <hip/hip_runtime.h>
#include <math.h>

#define BLK 256
#define UNR 8

// One block per (direction via blockIdx.z, batch via blockIdx.y, query-chunk via blockIdx.x).
// Stages the full reference cloud (nR points) into LDS as float4 (x,y,z,norm),
// each thread owns one query point and min-reduces squared distance over all refs.
// Block then sum-reduces its 256 mins and writes one partial sum.
__global__ __launch_bounds__(BLK) void chamfer_min_kernel(
    const float* __restrict__ P,   // [B,N,3] points
    const float* __restrict__ G,   // [B,M,3] gts
    float* __restrict__ partial,   // [2][B][chunks]
    int N, int M, int chunks)
{
    __shared__ float4 lds[4096];   // 64 KB exactly

    const int dir   = blockIdx.z;         // 0: points->gts (p2g), 1: gts->points (g2p)
    const int b     = blockIdx.y;
    const int chunk = blockIdx.x;
    const int B     = gridDim.y;

    const float* __restrict__ Q = dir ? G : P;
    const float* __restrict__ R = dir ? P : G;
    const int nQ = dir ? M : N;
    const int nR = dir ? N : M;

    const float* Qb = Q + (size_t)b * nQ * 3;
    const float* Rb = R + (size_t)b * nR * 3;

    // stage refs into LDS: (x, y, z, x^2+y^2+z^2)
    for (int j = threadIdx.x; j < nR; j += BLK) {
        float x = Rb[3 * j + 0];
        float y = Rb[3 * j + 1];
        float z = Rb[3 * j + 2];
        lds[j] = make_float4(x, y, z, fmaf(x, x, fmaf(y, y, z * z)));
    }
    __syncthreads();

    const int qi = chunk * BLK + threadIdx.x;
    float px = 0.f, py = 0.f, pz = 0.f;
    if (qi < nQ) {
        px = Qb[3 * qi + 0];
        py = Qb[3 * qi + 1];
        pz = Qb[3 * qi + 2];
    }
    const float pn  = fmaf(px, px, fmaf(py, py, pz * pz));
    const float m2x = -2.f * px, m2y = -2.f * py, m2z = -2.f * pz;

    // 8 independent min accumulators to break the fmin dependency chain
    float mnv[UNR];
#pragma unroll
    for (int u = 0; u < UNR; ++u) mnv[u] = 3.4e38f;

    for (int j = 0; j < nR; j += UNR) {
#pragma unroll
        for (int u = 0; u < UNR; ++u) {
            float4 g = lds[j + u];           // broadcast ds_read_b128
            float t = pn + g.w;              // pn + gn
            t = fmaf(m2x, g.x, t);           // -2 p.g
            t = fmaf(m2y, g.y, t);
            t = fmaf(m2z, g.z, t);
            mnv[u] = fminf(mnv[u], t);
        }
    }
    float mn = fminf(fminf(fminf(mnv[0], mnv[1]), fminf(mnv[2], mnv[3])),
                     fminf(fminf(mnv[4], mnv[5]), fminf(mnv[6], mnv[7])));
    mn = fmaxf(mn, 0.0f);                    // matches reference maximum(d, 0)
    if (qi >= nQ) mn = 0.0f;

    // block sum reduction (reuse LDS after barrier)
    __syncthreads();
    float* red = (float*)lds;
    red[threadIdx.x] = mn;
    __syncthreads();
    if (threadIdx.x < 128) red[threadIdx.x] += red[threadIdx.x + 128];
    __syncthreads();
    if (threadIdx.x < 64) {
        float v = red[threadIdx.x] + red[threadIdx.x + 64];
#pragma unroll
        for (int off = 32; off > 0; off >>= 1)
            v += __shfl_down(v, off, 64);
        if (threadIdx.x == 0)
            partial[((size_t)dir * B + b) * chunks + chunk] = v;
    }
}

// Single block: combine [2][B][chunks] partial sums into the 3 scalar outputs.
__global__ __launch_bounds__(BLK) void chamfer_final(
    const float* __restrict__ partial, float* __restrict__ out,
    int B, int chunks, int N, int M)
{
    __shared__ float s[2 * 8 * 16];
    __shared__ float r[16];
    const int total = 2 * B * chunks;
    if (threadIdx.x < total) s[threadIdx.x] = partial[threadIdx.x];
    __syncthreads();
    if (threadIdx.x < 2 * B) {
        float sum = 0.f;
        for (int c = 0; c < chunks; ++c) sum += s[threadIdx.x * chunks + c];
        const int dir = threadIdx.x / B;
        const float denom = dir ? (float)M : (float)N;
        r[threadIdx.x] = sqrtf(sum / denom);
    }
    __syncthreads();
    if (threadIdx.x == 0) {
        float p2g = 0.f, g2p = 0.f;
        for (int b = 0; b < B; ++b) { p2g += r[b]; g2p += r[B + b]; }
        p2g /= (float)B;
        g2p /= (float)B;
        out[0] = 0.5f * (p2g + g2p);   // mean loss
        out[1] = p2g;                  // mean p2g
        out[2] = g2p;                  // mean g2p
    }
}

extern "C" void kernel_launch(void* const* d_in, const int* in_sizes, int n_in,
                              void* d_out, int out_size, void* d_ws, size_t ws_size,
                              hipStream_t stream) {
    const float* points = (const float*)d_in[0];
    const float* gts    = (const float*)d_in[1];
    float* out = (float*)d_out;
    float* partial = (float*)d_ws;

    const int B = 8, N = 4096, M = 4096;
    const int chunks = N / BLK;            // 16 (N == M here)

    dim3 grid(chunks, B, 2);               // 256 blocks: full chip
    chamfer_min_kernel<<<grid, BLK, 0, stream>>>(points, gts, partial, N, M, chunks);
    chamfer_final<<<1, BLK, 0, stream>>>(partial, out, B, chunks, N, M);
}

// Round 2
// 44.516 us; speedup vs baseline: 1.9225x; 1.9225x over previous
//
#include <hip/hip_runtime.h>
#include <math.h>

#define BLK 256
#define QPT 8            // query points per thread
#define RS  8            // ref-chunk splits per (dir, batch)
#define NPTS 4096
#define RCH (NPTS / RS)  // 512 refs per chunk
#define B   8

// Stage 1: one block per (dir, batch, qchunk, refchunk).
// 256 threads x QPT=8 queries each = 2048 queries/block -> qchunks = 2.
// Refs split RS=8 ways -> 512 refs staged in 8KB LDS.
// Inner loop: 1 broadcast ds_read_b128 per ref, 4 VALU per (ref, query)
// (pn deferred to stage 2 -> t = fma(m2x,gx,gn); fma; fma; min).
__global__ __launch_bounds__(BLK) void chamfer_partial_kernel(
    const float* __restrict__ P,   // [B,N,3]
    const float* __restrict__ G,   // [B,M,3]
    float* __restrict__ partial)   // [2][B][RS][NPTS] per-query partial mins (no pn)
{
    __shared__ float4 lds[RCH];

    const int dir = blockIdx.z;
    const int b   = blockIdx.y;
    const int qc  = blockIdx.x / RS;   // 0..1
    const int r   = blockIdx.x % RS;   // 0..7

    const float* Qb = (dir ? G : P) + (size_t)b * NPTS * 3;
    const float* Rb = (dir ? P : G) + (size_t)b * NPTS * 3;

    // stage this block's ref chunk: (x, y, z, ||g||^2)
    const int j0 = r * RCH;
    for (int j = threadIdx.x; j < RCH; j += BLK) {
        float x = Rb[3 * (j0 + j) + 0];
        float y = Rb[3 * (j0 + j) + 1];
        float z = Rb[3 * (j0 + j) + 2];
        lds[j] = make_float4(x, y, z, fmaf(x, x, fmaf(y, y, z * z)));
    }
    __syncthreads();

    float m2x[QPT], m2y[QPT], m2z[QPT], acc[QPT];
#pragma unroll
    for (int q = 0; q < QPT; ++q) {
        const int qi = qc * (BLK * QPT) + q * BLK + threadIdx.x;
        m2x[q] = -2.f * Qb[3 * qi + 0];
        m2y[q] = -2.f * Qb[3 * qi + 1];
        m2z[q] = -2.f * Qb[3 * qi + 2];
        acc[q] = 3.4e38f;
    }

    for (int j = 0; j < RCH; j += 4) {
        const float4 g0 = lds[j + 0];
        const float4 g1 = lds[j + 1];
        const float4 g2 = lds[j + 2];
        const float4 g3 = lds[j + 3];
#pragma unroll
        for (int q = 0; q < QPT; ++q) {
            float t0 = fmaf(m2x[q], g0.x, g0.w);
            t0 = fmaf(m2y[q], g0.y, t0);
            t0 = fmaf(m2z[q], g0.z, t0);
            float t1 = fmaf(m2x[q], g1.x, g1.w);
            t1 = fmaf(m2y[q], g1.y, t1);
            t1 = fmaf(m2z[q], g1.z, t1);
            float t2 = fmaf(m2x[q], g2.x, g2.w);
            t2 = fmaf(m2y[q], g2.y, t2);
            t2 = fmaf(m2z[q], g2.z, t2);
            float t3 = fmaf(m2x[q], g3.x, g3.w);
            t3 = fmaf(m2y[q], g3.y, t3);
            t3 = fmaf(m2z[q], g3.z, t3);
            // nested fminf -> candidate for v_min3_f32 fusion
            acc[q] = fminf(fminf(t0, t1), fminf(fminf(t2, t3), acc[q]));
        }
    }

#pragma unroll
    for (int q = 0; q < QPT; ++q) {
        const int qi = qc * (BLK * QPT) + q * BLK + threadIdx.x;
        partial[(((size_t)dir * B + b) * RS + r) * NPTS + qi] = acc[q];
    }
}

// Stage 2: one block per (dir, batch). Min-combine the RS partials per query,
// add pn, clamp at 0, sum, sqrt(mean) -> r16[dir*B+b].
__global__ __launch_bounds__(BLK) void chamfer_reduce_kernel(
    const float* __restrict__ P, const float* __restrict__ G,
    const float* __restrict__ partial, float* __restrict__ r16)
{
    const int dir = blockIdx.x >> 3;
    const int b   = blockIdx.x & 7;
    const float* Qb   = (dir ? G : P) + (size_t)b * NPTS * 3;
    const float* base = partial + ((size_t)dir * B + b) * RS * NPTS;

    float sum = 0.f;
    for (int qq = 0; qq < NPTS / BLK; ++qq) {
        const int q = qq * BLK + threadIdx.x;
        float mn = base[q];
#pragma unroll
        for (int rr = 1; rr < RS; ++rr) mn = fminf(mn, base[(size_t)rr * NPTS + q]);
        const float x = Qb[3 * q + 0];
        const float y = Qb[3 * q + 1];
        const float z = Qb[3 * q + 2];
        const float pn = fmaf(x, x, fmaf(y, y, z * z));
        sum += fmaxf(pn + mn, 0.f);
    }

    __shared__ float red[BLK];
    red[threadIdx.x] = sum;
    __syncthreads();
    if (threadIdx.x < 128) red[threadIdx.x] += red[threadIdx.x + 128];
    __syncthreads();
    if (threadIdx.x < 64) {
        float v = red[threadIdx.x] + red[threadIdx.x + 64];
#pragma unroll
        for (int off = 32; off > 0; off >>= 1) v += __shfl_down(v, off, 64);
        if (threadIdx.x == 0) r16[blockIdx.x] = sqrtf(v / (float)NPTS);
    }
}

// Stage 3: combine the 16 per-(dir,batch) values into the 3 scalar outputs.
__global__ __launch_bounds__(64) void chamfer_final_kernel(
    const float* __restrict__ r16, float* __restrict__ out)
{
    if (threadIdx.x == 0) {
        float p2g = 0.f, g2p = 0.f;
        for (int bb = 0; bb < B; ++bb) { p2g += r16[bb]; g2p += r16[B + bb]; }
        p2g *= (1.0f / B);
        g2p *= (1.0f / B);
        out[0] = 0.5f * (p2g + g2p);
        out[1] = p2g;
        out[2] = g2p;
    }
}

extern "C" void kernel_launch(void* const* d_in, const int* in_sizes, int n_in,
                              void* d_out, int out_size, void* d_ws, size_t ws_size,
                              hipStream_t stream) {
    const float* points = (const float*)d_in[0];
    const float* gts    = (const float*)d_in[1];
    float* out = (float*)d_out;

    float* partial = (float*)d_ws;                       // 2*B*RS*NPTS floats = 2MB
    float* r16     = partial + (size_t)2 * B * RS * NPTS;

    const int qchunks = NPTS / (BLK * QPT);              // 2
    dim3 grid1(qchunks * RS, B, 2);                      // 16 x 8 x 2 = 256 blocks
    chamfer_partial_kernel<<<grid1, BLK, 0, stream>>>(points, gts, partial);

    chamfer_reduce_kernel<<<dim3(2 * B), BLK, 0, stream>>>(points, gts, partial, r16);

    chamfer_final_kernel<<<dim3(1), 64, 0, stream>>>(r16, out);
}

// Round 3
// 31.778 us; speedup vs baseline: 2.6931x; 1.4008x over previous
//
#include <hip/hip_runtime.h>
#include <math.h>

#define BLK  256
#define NPTS 4096
#define B    8
#define SP   8     // stage-2 split per (dir,b)

#define FOREACH_Q(OP) OP(0) OP(1) OP(2) OP(3) OP(4) OP(5) OP(6) OP(7)

// Stage 1: one block per (dir, batch, qchunk, refchunk). grid.x = 2*RS.
// 256 threads x 8 queries = 2048 queries/block (qchunks=2).
// Refs split RS ways -> NPTS/RS refs staged in LDS as (x,y,z,||g||^2).
// Inner loop: 4 broadcast ds_read_b128 + per query 12 fma + 2 min3.
// Queries live in explicitly-named scalars so the compiler cannot re-roll.
template<int RS>
__global__ __launch_bounds__(BLK, 2) void chamfer_partial(
    const float* __restrict__ P,
    const float* __restrict__ G,
    float* __restrict__ partial)   // [2][B][RS][NPTS] partial mins (pn deferred)
{
    constexpr int RCH = NPTS / RS;
    __shared__ float4 lds[RCH];

    const int dir = blockIdx.z;
    const int b   = blockIdx.y;
    const int qc  = blockIdx.x / RS;
    const int r   = blockIdx.x % RS;

    const float* __restrict__ Qb = (dir ? G : P) + (size_t)b * NPTS * 3;
    const float* __restrict__ Rb = (dir ? P : G) + (size_t)b * NPTS * 3;

    const int j0 = r * RCH;
    for (int j = threadIdx.x; j < RCH; j += BLK) {
        float x = Rb[3 * (j0 + j) + 0];
        float y = Rb[3 * (j0 + j) + 1];
        float z = Rb[3 * (j0 + j) + 2];
        lds[j] = make_float4(x, y, z, fmaf(x, x, fmaf(y, y, z * z)));
    }
    __syncthreads();

    const int qbase = qc * (BLK * 8);

#define DECLQ(i) float m2x##i, m2y##i, m2z##i, acc##i;
    FOREACH_Q(DECLQ)
#undef DECLQ

#define LOADQ(i) { const int qi = qbase + (i) * BLK + threadIdx.x;           \
        m2x##i = -2.f * Qb[3 * qi + 0];                                      \
        m2y##i = -2.f * Qb[3 * qi + 1];                                      \
        m2z##i = -2.f * Qb[3 * qi + 2];                                      \
        acc##i = 3.4e38f; }
    FOREACH_Q(LOADQ)
#undef LOADQ

#pragma unroll 2
    for (int j = 0; j < RCH; j += 4) {
        const float4 g0 = lds[j + 0];
        const float4 g1 = lds[j + 1];
        const float4 g2 = lds[j + 2];
        const float4 g3 = lds[j + 3];
#define EVALQ(i) {                                                           \
        float t0 = fmaf(m2x##i, g0.x, g0.w);                                 \
        t0 = fmaf(m2y##i, g0.y, t0);                                         \
        t0 = fmaf(m2z##i, g0.z, t0);                                         \
        float t1 = fmaf(m2x##i, g1.x, g1.w);                                 \
        t1 = fmaf(m2y##i, g1.y, t1);                                         \
        t1 = fmaf(m2z##i, g1.z, t1);                                         \
        float t2 = fmaf(m2x##i, g2.x, g2.w);                                 \
        t2 = fmaf(m2y##i, g2.y, t2);                                         \
        t2 = fmaf(m2z##i, g2.z, t2);                                         \
        float t3 = fmaf(m2x##i, g3.x, g3.w);                                 \
        t3 = fmaf(m2y##i, g3.y, t3);                                         \
        t3 = fmaf(m2z##i, g3.z, t3);                                         \
        acc##i = fminf(fminf(t0, t1), fminf(fminf(t2, t3), acc##i)); }
        FOREACH_Q(EVALQ)
#undef EVALQ
    }

    float* out_base = partial + (((size_t)dir * B + b) * RS + r) * NPTS;
#define STOREQ(i) out_base[qbase + (i) * BLK + threadIdx.x] = acc##i;
    FOREACH_Q(STOREQ)
#undef STOREQ
}

// Stage 2: grid = 2*B*SP blocks; each handles NPTS/SP queries of one (dir,b):
// min-combine RS partials (fully unrolled), add pn, clamp, block-sum.
template<int RS>
__global__ __launch_bounds__(BLK) void chamfer_reduce(
    const float* __restrict__ P, const float* __restrict__ G,
    const float* __restrict__ partial, float* __restrict__ sums)
{
    const int dirb = blockIdx.x / SP;      // 0..15
    const int sp   = blockIdx.x % SP;
    const int dir  = dirb >> 3;
    const int b    = dirb & 7;
    const float* __restrict__ Qb = (dir ? G : P) + (size_t)b * NPTS * 3;
    const float* __restrict__ base = partial + (size_t)dirb * RS * NPTS;

    float sum = 0.f;
#pragma unroll
    for (int i = 0; i < NPTS / SP / BLK; ++i) {
        const int q = sp * (NPTS / SP) + i * BLK + threadIdx.x;
        float mn = base[q];
#pragma unroll
        for (int rr = 1; rr < RS; ++rr) mn = fminf(mn, base[(size_t)rr * NPTS + q]);
        const float x = Qb[3 * q + 0];
        const float y = Qb[3 * q + 1];
        const float z = Qb[3 * q + 2];
        sum += fmaxf(fmaf(x, x, fmaf(y, y, z * z)) + mn, 0.f);
    }

    __shared__ float red[BLK];
    red[threadIdx.x] = sum;
    __syncthreads();
    if (threadIdx.x < 128) red[threadIdx.x] += red[threadIdx.x + 128];
    __syncthreads();
    if (threadIdx.x < 64) {
        float v = red[threadIdx.x] + red[threadIdx.x + 64];
#pragma unroll
        for (int off = 32; off > 0; off >>= 1) v += __shfl_down(v, off, 64);
        if (threadIdx.x == 0) sums[blockIdx.x] = v;   // [dirb][sp]
    }
}

// Stage 3: 16 x sqrt(mean) then the 3 scalar outputs.
__global__ __launch_bounds__(64) void chamfer_final(
    const float* __restrict__ sums, float* __restrict__ out)
{
    __shared__ float r16[16];
    if (threadIdx.x < 16) {
        float s = 0.f;
#pragma unroll
        for (int sp = 0; sp < SP; ++sp) s += sums[threadIdx.x * SP + sp];
        r16[threadIdx.x] = sqrtf(s / (float)NPTS);
    }
    __syncthreads();
    if (threadIdx.x == 0) {
        float p2g = 0.f, g2p = 0.f;
#pragma unroll
        for (int bb = 0; bb < B; ++bb) { p2g += r16[bb]; g2p += r16[B + bb]; }
        p2g *= (1.0f / B);
        g2p *= (1.0f / B);
        out[0] = 0.5f * (p2g + g2p);
        out[1] = p2g;
        out[2] = g2p;
    }
}

extern "C" void kernel_launch(void* const* d_in, const int* in_sizes, int n_in,
                              void* d_out, int out_size, void* d_ws, size_t ws_size,
                              hipStream_t stream) {
    const float* points = (const float*)d_in[0];
    const float* gts    = (const float*)d_in[1];
    float* out = (float*)d_out;
    float* partial = (float*)d_ws;

    const size_t need16 = (size_t)2 * B * 16 * NPTS * 4 + 1024;
    const bool use16 = (ws_size >= need16);
    const int RS = use16 ? 16 : 8;
    float* sums = partial + (size_t)2 * B * RS * NPTS;

    if (use16) {
        dim3 grid1(2 * 16, B, 2);   // 512 blocks -> 2 blocks/CU
        chamfer_partial<16><<<grid1, BLK, 0, stream>>>(points, gts, partial);
        chamfer_reduce<16><<<dim3(2 * B * SP), BLK, 0, stream>>>(points, gts, partial, sums);
    } else {
        dim3 grid1(2 * 8, B, 2);
        chamfer_partial<8><<<grid1, BLK, 0, stream>>>(points, gts, partial);
        chamfer_reduce<8><<<dim3(2 * B * SP), BLK, 0, stream>>>(points, gts, partial, sums);
    }
    chamfer_final<<<dim3(1), 64, 0, stream>>>(sums, out);
}

// Round 4
// 31.700 us; speedup vs baseline: 2.6997x; 1.0025x over previous
//
#include <hip/hip_runtime.h>
#include <math.h>

#define BLK  256
#define NPTS 4096
#define B    8
#define SP   8     // stage-2 split per (dir,b)

#define FOREACH_Q(OP) OP(0) OP(1) OP(2) OP(3) OP(4) OP(5) OP(6) OP(7)

// Stage 1: one block per (dir, batch, qchunk, refchunk). grid.x = 2*RS.
// 256 threads x 8 queries = 2048 queries/block (qchunks=2).
// Refs split RS ways -> NPTS/RS refs staged in LDS as (x,y,z,||g||^2).
// Inner loop: 4 broadcast ds_read_b128 + per query 12 fma + 2 min3.
// Queries live in explicitly-named scalars so the compiler cannot re-roll.
template<int RS>
__global__ __launch_bounds__(BLK, 2) void chamfer_partial(
    const float* __restrict__ P,
    const float* __restrict__ G,
    float* __restrict__ partial)   // [2][B][RS][NPTS] partial mins (pn deferred)
{
    constexpr int RCH = NPTS / RS;
    __shared__ float4 lds[RCH];

    const int dir = blockIdx.z;
    const int b   = blockIdx.y;
    const int qc  = blockIdx.x / RS;
    const int r   = blockIdx.x % RS;

    const float* __restrict__ Qb = (dir ? G : P) + (size_t)b * NPTS * 3;
    const float* __restrict__ Rb = (dir ? P : G) + (size_t)b * NPTS * 3;

    const int j0 = r * RCH;
    for (int j = threadIdx.x; j < RCH; j += BLK) {
        float x = Rb[3 * (j0 + j) + 0];
        float y = Rb[3 * (j0 + j) + 1];
        float z = Rb[3 * (j0 + j) + 2];
        lds[j] = make_float4(x, y, z, fmaf(x, x, fmaf(y, y, z * z)));
    }
    __syncthreads();

    const int qbase = qc * (BLK * 8);

#define DECLQ(i) float m2x##i, m2y##i, m2z##i, acc##i;
    FOREACH_Q(DECLQ)
#undef DECLQ

#define LOADQ(i) { const int qi = qbase + (i) * BLK + threadIdx.x;           \
        m2x##i = -2.f * Qb[3 * qi + 0];                                      \
        m2y##i = -2.f * Qb[3 * qi + 1];                                      \
        m2z##i = -2.f * Qb[3 * qi + 2];                                      \
        acc##i = 3.4e38f; }
    FOREACH_Q(LOADQ)
#undef LOADQ

#pragma unroll 2
    for (int j = 0; j < RCH; j += 4) {
        const float4 g0 = lds[j + 0];
        const float4 g1 = lds[j + 1];
        const float4 g2 = lds[j + 2];
        const float4 g3 = lds[j + 3];
#define EVALQ(i) {                                                           \
        float t0 = fmaf(m2x##i, g0.x, g0.w);                                 \
        t0 = fmaf(m2y##i, g0.y, t0);                                         \
        t0 = fmaf(m2z##i, g0.z, t0);                                         \
        float t1 = fmaf(m2x##i, g1.x, g1.w);                                 \
        t1 = fmaf(m2y##i, g1.y, t1);                                         \
        t1 = fmaf(m2z##i, g1.z, t1);                                         \
        float t2 = fmaf(m2x##i, g2.x, g2.w);                                 \
        t2 = fmaf(m2y##i, g2.y, t2);                                         \
        t2 = fmaf(m2z##i, g2.z, t2);                                         \
        float t3 = fmaf(m2x##i, g3.x, g3.w);                                 \
        t3 = fmaf(m2y##i, g3.y, t3);                                         \
        t3 = fmaf(m2z##i, g3.z, t3);                                         \
        acc##i = fminf(fminf(t0, t1), fminf(fminf(t2, t3), acc##i)); }
        FOREACH_Q(EVALQ)
#undef EVALQ
    }

    float* out_base = partial + (((size_t)dir * B + b) * RS + r) * NPTS;
#define STOREQ(i) out_base[qbase + (i) * BLK + threadIdx.x] = acc##i;
    FOREACH_Q(STOREQ)
#undef STOREQ
}

// Stage 2: grid = 2*B*SP blocks; each handles NPTS/SP queries of one (dir,b):
// min-combine RS partials (fully unrolled), add pn, clamp, block-sum.
template<int RS>
__global__ __launch_bounds__(BLK) void chamfer_reduce(
    const float* __restrict__ P, const float* __restrict__ G,
    const float* __restrict__ partial, float* __restrict__ sums)
{
    const int dirb = blockIdx.x / SP;      // 0..15
    const int sp   = blockIdx.x % SP;
    const int dir  = dirb >> 3;
    const int b    = dirb & 7;
    const float* __restrict__ Qb = (dir ? G : P) + (size_t)b * NPTS * 3;
    const float* __restrict__ base = partial + (size_t)dirb * RS * NPTS;

    float sum = 0.f;
#pragma unroll
    for (int i = 0; i < NPTS / SP / BLK; ++i) {
        const int q = sp * (NPTS / SP) + i * BLK + threadIdx.x;
        float mn = base[q];
#pragma unroll
        for (int rr = 1; rr < RS; ++rr) mn = fminf(mn, base[(size_t)rr * NPTS + q]);
        const float x = Qb[3 * q + 0];
        const float y = Qb[3 * q + 1];
        const float z = Qb[3 * q + 2];
        sum += fmaxf(fmaf(x, x, fmaf(y, y, z * z)) + mn, 0.f);
    }

    __shared__ float red[BLK];
    red[threadIdx.x] = sum;
    __syncthreads();
    if (threadIdx.x < 128) red[threadIdx.x] += red[threadIdx.x + 128];
    __syncthreads();
    if (threadIdx.x < 64) {
        float v = red[threadIdx.x] + red[threadIdx.x + 64];
#pragma unroll
        for (int off = 32; off > 0; off >>= 1) v += __shfl_down(v, off, 64);
        if (threadIdx.x == 0) sums[blockIdx.x] = v;   // [dirb][sp]
    }
}

// Stage 3: 16 x sqrt(mean) then the 3 scalar outputs.
__global__ __launch_bounds__(64) void chamfer_final(
    const float* __restrict__ sums, float* __restrict__ out)
{
    __shared__ float r16[16];
    if (threadIdx.x < 16) {
        float s = 0.f;
#pragma unroll
        for (int sp = 0; sp < SP; ++sp) s += sums[threadIdx.x * SP + sp];
        r16[threadIdx.x] = sqrtf(s / (float)NPTS);
    }
    __syncthreads();
    if (threadIdx.x == 0) {
        float p2g = 0.f, g2p = 0.f;
#pragma unroll
        for (int bb = 0; bb < B; ++bb) { p2g += r16[bb]; g2p += r16[B + bb]; }
        p2g *= (1.0f / B);
        g2p *= (1.0f / B);
        out[0] = 0.5f * (p2g + g2p);
        out[1] = p2g;
        out[2] = g2p;
    }
}

extern "C" void kernel_launch(void* const* d_in, const int* in_sizes, int n_in,
                              void* d_out, int out_size, void* d_ws, size_t ws_size,
                              hipStream_t stream) {
    const float* points = (const float*)d_in[0];
    const float* gts    = (const float*)d_in[1];
    float* out = (float*)d_out;
    float* partial = (float*)d_ws;

    const size_t need16 = (size_t)2 * B * 16 * NPTS * 4 + 1024;
    const bool use16 = (ws_size >= need16);
    const int RS = use16 ? 16 : 8;
    float* sums = partial + (size_t)2 * B * RS * NPTS;

    if (use16) {
        dim3 grid1(2 * 16, B, 2);   // 512 blocks -> 2 blocks/CU
        chamfer_partial<16><<<grid1, BLK, 0, stream>>>(points, gts, partial);
        chamfer_reduce<16><<<dim3(2 * B * SP), BLK, 0, stream>>>(points, gts, partial, sums);
    } else {
        dim3 grid1(2 * 8, B, 2);
        chamfer_partial<8><<<grid1, BLK, 0, stream>>>(points, gts, partial);
        chamfer_reduce<8><<<dim3(2 * B * SP), BLK, 0, stream>>>(points, gts, partial, sums);
    }
    chamfer_final<<<dim3(1), 64, 0, stream>>>(sums, out);
}

// Round 5
// 31.510 us; speedup vs baseline: 2.7160x; 1.0060x over previous
//
#include <hip/hip_runtime.h>
#include <math.h>

#define BLK  256
#define NPTS 4096
#define B    8
#define SP   8     // stage-2 split per (dir,b)

#define FOREACH_Q(OP) OP(0) OP(1) OP(2) OP(3) OP(4) OP(5) OP(6) OP(7)

// Stage 1: one block per (dir, batch, qchunk, refchunk). grid.x = 2*RS.
// 256 threads x 8 queries = 2048 queries/block (qchunks=2).
// Refs split RS ways -> NPTS/RS refs staged in LDS as (x,y,z,||g||^2).
// Inner loop: 4 broadcast ds_read_b128 + per query 12 fma + 2 min3.
// Queries live in explicitly-named scalars so the compiler cannot re-roll.
template<int RS>
__global__ __launch_bounds__(BLK, 2) void chamfer_partial(
    const float* __restrict__ P,
    const float* __restrict__ G,
    float* __restrict__ partial)   // [2][B][RS][NPTS] partial mins (pn deferred)
{
    constexpr int RCH = NPTS / RS;
    __shared__ float4 lds[RCH];

    const int dir = blockIdx.z;
    const int b   = blockIdx.y;
    const int qc  = blockIdx.x / RS;
    const int r   = blockIdx.x % RS;

    const float* __restrict__ Qb = (dir ? G : P) + (size_t)b * NPTS * 3;
    const float* __restrict__ Rb = (dir ? P : G) + (size_t)b * NPTS * 3;

    const int j0 = r * RCH;
    for (int j = threadIdx.x; j < RCH; j += BLK) {
        float x = Rb[3 * (j0 + j) + 0];
        float y = Rb[3 * (j0 + j) + 1];
        float z = Rb[3 * (j0 + j) + 2];
        lds[j] = make_float4(x, y, z, fmaf(x, x, fmaf(y, y, z * z)));
    }
    __syncthreads();

    const int qbase = qc * (BLK * 8);

#define DECLQ(i) float m2x##i, m2y##i, m2z##i, acc##i;
    FOREACH_Q(DECLQ)
#undef DECLQ

#define LOADQ(i) { const int qi = qbase + (i) * BLK + threadIdx.x;           \
        m2x##i = -2.f * Qb[3 * qi + 0];                                      \
        m2y##i = -2.f * Qb[3 * qi + 1];                                      \
        m2z##i = -2.f * Qb[3 * qi + 2];                                      \
        acc##i = 3.4e38f; }
    FOREACH_Q(LOADQ)
#undef LOADQ

#pragma unroll 2
    for (int j = 0; j < RCH; j += 4) {
        const float4 g0 = lds[j + 0];
        const float4 g1 = lds[j + 1];
        const float4 g2 = lds[j + 2];
        const float4 g3 = lds[j + 3];
#define EVALQ(i) {                                                           \
        float t0 = fmaf(m2x##i, g0.x, g0.w);                                 \
        t0 = fmaf(m2y##i, g0.y, t0);                                         \
        t0 = fmaf(m2z##i, g0.z, t0);                                         \
        float t1 = fmaf(m2x##i, g1.x, g1.w);                                 \
        t1 = fmaf(m2y##i, g1.y, t1);                                         \
        t1 = fmaf(m2z##i, g1.z, t1);                                         \
        float t2 = fmaf(m2x##i, g2.x, g2.w);                                 \
        t2 = fmaf(m2y##i, g2.y, t2);                                         \
        t2 = fmaf(m2z##i, g2.z, t2);                                         \
        float t3 = fmaf(m2x##i, g3.x, g3.w);                                 \
        t3 = fmaf(m2y##i, g3.y, t3);                                         \
        t3 = fmaf(m2z##i, g3.z, t3);                                         \
        acc##i = fminf(fminf(t0, t1), fminf(fminf(t2, t3), acc##i)); }
        FOREACH_Q(EVALQ)
#undef EVALQ
    }

    float* out_base = partial + (((size_t)dir * B + b) * RS + r) * NPTS;
#define STOREQ(i) out_base[qbase + (i) * BLK + threadIdx.x] = acc##i;
    FOREACH_Q(STOREQ)
#undef STOREQ
}

// Stage 2: grid = 2*B*SP blocks; each handles NPTS/SP queries of one (dir,b):
// min-combine RS partials (fully unrolled), add pn, clamp, block-sum.
template<int RS>
__global__ __launch_bounds__(BLK) void chamfer_reduce(
    const float* __restrict__ P, const float* __restrict__ G,
    const float* __restrict__ partial, float* __restrict__ sums)
{
    const int dirb = blockIdx.x / SP;      // 0..15
    const int sp   = blockIdx.x % SP;
    const int dir  = dirb >> 3;
    const int b    = dirb & 7;
    const float* __restrict__ Qb = (dir ? G : P) + (size_t)b * NPTS * 3;
    const float* __restrict__ base = partial + (size_t)dirb * RS * NPTS;

    float sum = 0.f;
#pragma unroll
    for (int i = 0; i < NPTS / SP / BLK; ++i) {
        const int q = sp * (NPTS / SP) + i * BLK + threadIdx.x;
        float mn = base[q];
#pragma unroll
        for (int rr = 1; rr < RS; ++rr) mn = fminf(mn, base[(size_t)rr * NPTS + q]);
        const float x = Qb[3 * q + 0];
        const float y = Qb[3 * q + 1];
        const float z = Qb[3 * q + 2];
        sum += fmaxf(fmaf(x, x, fmaf(y, y, z * z)) + mn, 0.f);
    }

    __shared__ float red[BLK];
    red[threadIdx.x] = sum;
    __syncthreads();
    if (threadIdx.x < 128) red[threadIdx.x] += red[threadIdx.x + 128];
    __syncthreads();
    if (threadIdx.x < 64) {
        float v = red[threadIdx.x] + red[threadIdx.x + 64];
#pragma unroll
        for (int off = 32; off > 0; off >>= 1) v += __shfl_down(v, off, 64);
        if (threadIdx.x == 0) sums[blockIdx.x] = v;   // [dirb][sp]
    }
}

// Stage 3: 16 x sqrt(mean) then the 3 scalar outputs.
__global__ __launch_bounds__(64) void chamfer_final(
    const float* __restrict__ sums, float* __restrict__ out)
{
    __shared__ float r16[16];
    if (threadIdx.x < 16) {
        float s = 0.f;
#pragma unroll
        for (int sp = 0; sp < SP; ++sp) s += sums[threadIdx.x * SP + sp];
        r16[threadIdx.x] = sqrtf(s / (float)NPTS);
    }
    __syncthreads();
    if (threadIdx.x == 0) {
        float p2g = 0.f, g2p = 0.f;
#pragma unroll
        for (int bb = 0; bb < B; ++bb) { p2g += r16[bb]; g2p += r16[B + bb]; }
        p2g *= (1.0f / B);
        g2p *= (1.0f / B);
        out[0] = 0.5f * (p2g + g2p);
        out[1] = p2g;
        out[2] = g2p;
    }
}

extern "C" void kernel_launch(void* const* d_in, const int* in_sizes, int n_in,
                              void* d_out, int out_size, void* d_ws, size_t ws_size,
                              hipStream_t stream) {
    const float* points = (const float*)d_in[0];
    const float* gts    = (const float*)d_in[1];
    float* out = (float*)d_out;
    float* partial = (float*)d_ws;

    const size_t need16 = (size_t)2 * B * 16 * NPTS * 4 + 1024;
    const bool use16 = (ws_size >= need16);
    const int RS = use16 ? 16 : 8;
    float* sums = partial + (size_t)2 * B * RS * NPTS;

    if (use16) {
        dim3 grid1(2 * 16, B, 2);   // 512 blocks -> 2 blocks/CU
        chamfer_partial<16><<<grid1, BLK, 0, stream>>>(points, gts, partial);
        chamfer_reduce<16><<<dim3(2 * B * SP), BLK, 0, stream>>>(points, gts, partial, sums);
    } else {
        dim3 grid1(2 * 8, B, 2);
        chamfer_partial<8><<<grid1, BLK, 0, stream>>>(points, gts, partial);
        chamfer_reduce<8><<<dim3(2 * B * SP), BLK, 0, stream>>>(points, gts, partial, sums);
    }
    chamfer_final<<<dim3(1), 64, 0, stream>>>(sums, out);
}